// Round 1
// baseline (12264.318 us; speedup 1.0000x reference)
//
#include <hip/hip_runtime.h>
#include <cmath>

#define NIN   128
#define NHID  32
#define CTS   16384
#define NCT   16
#define NBAGS (CTS / NCT)
#define SEG_STRIDE 33   // 32 weighted-H sums + 1 softmax denom

// Stage 1+2: per-row MLP + attention score, atomic segment accumulation of
//   num_j = sum_i exp(s_i) * H_ij   and   den = sum_i exp(s_i)
// (segment softmax weights cancel: P = num/den, identical to max-shifted ref)
__global__ __launch_bounds__(256) void rows_kernel(
    const float* __restrict__ X,
    const float* __restrict__ W1,
    const float* __restrict__ b1,
    const float* __restrict__ wc,
    const float* __restrict__ bc,
    const int*   __restrict__ batch,
    float* __restrict__ segacc,
    int n)
{
    __shared__ __align__(16) float w1s[NIN * NHID];  // 16 KB, [k][j]
    __shared__ float b1s[NHID];
    __shared__ float wcs[NHID];

    const int tid = threadIdx.x;
    for (int i = tid; i < NIN * NHID; i += 256) w1s[i] = W1[i];
    if (tid < NHID) { b1s[tid] = b1[tid]; wcs[tid] = wc[tid]; }
    __syncthreads();

    const long long idx = (long long)blockIdx.x * 256 + tid;
    const long long r0 = idx * 2;
    if (r0 >= n) return;
    const bool has2 = (r0 + 1) < n;

    const float4* __restrict__ xp0 = (const float4*)(X + (size_t)r0 * NIN);
    const float4* __restrict__ xp1 = (const float4*)(X + (size_t)(has2 ? r0 + 1 : r0) * NIN);

    float acc0[NHID], acc1[NHID];
#pragma unroll
    for (int j = 0; j < NHID; ++j) { acc0[j] = 0.f; acc1[j] = 0.f; }

#pragma unroll
    for (int kc = 0; kc < NIN / 32; ++kc) {   // 4 chunks of 32 k
        float4 x0[8], x1[8];
#pragma unroll
        for (int q = 0; q < 8; ++q) x0[q] = xp0[kc * 8 + q];
#pragma unroll
        for (int q = 0; q < 8; ++q) x1[q] = xp1[kc * 8 + q];
#pragma unroll
        for (int q = 0; q < 8; ++q) {
            const float a0[4] = {x0[q].x, x0[q].y, x0[q].z, x0[q].w};
            const float a1[4] = {x1[q].x, x1[q].y, x1[q].z, x1[q].w};
#pragma unroll
            for (int kk = 0; kk < 4; ++kk) {
                const int k = kc * 32 + q * 4 + kk;
                const float4* __restrict__ wrow = (const float4*)(w1s + k * NHID);
                const float u0 = a0[kk], u1 = a1[kk];
#pragma unroll
                for (int jq = 0; jq < 8; ++jq) {
                    const float4 w = wrow[jq];   // wave-uniform -> LDS broadcast
                    acc0[jq*4+0] += u0 * w.x;  acc1[jq*4+0] += u1 * w.x;
                    acc0[jq*4+1] += u0 * w.y;  acc1[jq*4+1] += u1 * w.y;
                    acc0[jq*4+2] += u0 * w.z;  acc1[jq*4+2] += u1 * w.z;
                    acc0[jq*4+3] += u0 * w.w;  acc1[jq*4+3] += u1 * w.w;
                }
            }
        }
    }

    const float bc0 = bc[0];
    float s0 = bc0, s1 = bc0;
#pragma unroll
    for (int j = 0; j < NHID; ++j) {
        float h0 = acc0[j] + b1s[j]; h0 = fmaxf(h0, 0.f); acc0[j] = h0; s0 += h0 * wcs[j];
        float h1 = acc1[j] + b1s[j]; h1 = fmaxf(h1, 0.f); acc1[j] = h1; s1 += h1 * wcs[j];
    }

    {
        const float e0 = expf(s0);
        const int seg0 = batch[r0];
        float* p0 = segacc + (size_t)seg0 * SEG_STRIDE;
#pragma unroll
        for (int j = 0; j < NHID; ++j) atomicAdd(p0 + j, e0 * acc0[j]);
        atomicAdd(p0 + NHID, e0);
    }
    if (has2) {
        const float e1 = expf(s1);
        const int seg1 = batch[r0 + 1];
        float* p1 = segacc + (size_t)seg1 * SEG_STRIDE;
#pragma unroll
        for (int j = 0; j < NHID; ++j) atomicAdd(p1 + j, e1 * acc1[j]);
        atomicAdd(p1 + NHID, e1);
    }
}

// Stage 3: per-bag cell-type softmax + output projection. One thread per bag.
__global__ __launch_bounds__(256) void bags_kernel(
    const float* __restrict__ segacc,
    const float* __restrict__ wct,
    const float* __restrict__ bct,
    const float* __restrict__ Wout,
    const float* __restrict__ bout,
    float* __restrict__ out)
{
    const int b = blockIdx.x * blockDim.x + threadIdx.x;
    if (b >= NBAGS) return;

    float wctr[NHID], wor[NHID];
#pragma unroll
    for (int j = 0; j < NHID; ++j) { wctr[j] = wct[j]; wor[j] = Wout[j]; }
    const float bct0 = bct[0];

    float logit[NCT], dout[NCT];
#pragma unroll
    for (int ct = 0; ct < NCT; ++ct) {
        const float* p = segacc + (size_t)(b * NCT + ct) * SEG_STRIDE;
        const float den = p[NHID];
        const float inv = den > 0.f ? 1.f / den : 0.f;  // empty segment -> P row = 0
        float t = 0.f, d = 0.f;
#pragma unroll
        for (int j = 0; j < NHID; ++j) {
            const float pj = p[j] * inv;
            t += pj * wctr[j];
            d += pj * wor[j];
        }
        logit[ct] = t + bct0;
        dout[ct]  = d;
    }

    float m = logit[0];
#pragma unroll
    for (int ct = 1; ct < NCT; ++ct) m = fmaxf(m, logit[ct]);
    float den = 0.f, acc = 0.f;
#pragma unroll
    for (int ct = 0; ct < NCT; ++ct) {
        const float e = expf(logit[ct] - m);
        den += e;
        acc += e * dout[ct];
    }
    out[b] = acc / den + bout[0];
}

extern "C" void kernel_launch(void* const* d_in, const int* in_sizes, int n_in,
                              void* d_out, int out_size, void* d_ws, size_t ws_size,
                              hipStream_t stream)
{
    const float* X    = (const float*)d_in[0];
    const float* W1   = (const float*)d_in[1];
    const float* b1   = (const float*)d_in[2];
    const float* wc   = (const float*)d_in[3];
    const float* bc   = (const float*)d_in[4];
    const float* wct  = (const float*)d_in[5];
    const float* bct  = (const float*)d_in[6];
    const float* Wout = (const float*)d_in[7];
    const float* bout = (const float*)d_in[8];
    const int*   batch= (const int*)d_in[9];
    const int n = in_sizes[9];   // number of rows (2,000,000)

    float* segacc = (float*)d_ws;   // CTS*33 floats = 2.16 MB of scratch
    hipMemsetAsync(segacc, 0, (size_t)CTS * SEG_STRIDE * sizeof(float), stream);

    const int threads = 256;
    const long long nthreads = ((long long)n + 1) / 2;   // 2 rows per thread
    const int blocks = (int)((nthreads + threads - 1) / threads);
    rows_kernel<<<blocks, threads, 0, stream>>>(X, W1, b1, wc, bc, batch, segacc, n);
    bags_kernel<<<(NBAGS + threads - 1) / threads, threads, 0, stream>>>(
        segacc, wct, bct, Wout, bout, (float*)d_out);
}